// Round 12
// baseline (70.832 us; speedup 1.0000x reference)
//
#include <hip/hip_runtime.h>
#include <hip/hip_bf16.h>
#include <math.h>

#define NUM_CLASSES 8192
#define FEAT_DIM    256
#define BATCH       1024
// TEMPERATURE = 0.1 -> logits = dot * 10

typedef long fp8x8;                                  // 8 fp8 in 2 VGPRs
typedef __attribute__((ext_vector_type(4))) float f32x4;

#define GLD16(gp, lp) __builtin_amdgcn_global_load_lds(                       \
    (const __attribute__((address_space(1))) void*)(gp),                      \
    (__attribute__((address_space(3))) void*)(lp), 16, 0, 0)

// ---------------------------------------------------------------------------
// Phase 1: EMA update + fp8 convert, prep-free. One wave per class.
// Blocks 0..31 also zero rowsum.
// ---------------------------------------------------------------------------
__global__ __launch_bounds__(256) void ema_convert_kernel(
    const float* __restrict__ feats, const float* __restrict__ proto,
    const int* __restrict__ labels, unsigned char* __restrict__ P8,
    float* __restrict__ rowsum) {
  __shared__ int lab_s[BATCH];
  const int tid = threadIdx.x;

  ((int4*)lab_s)[tid] = ((const int4*)labels)[tid];   // 256 x 16B = 4 KB
  if (blockIdx.x < 32) rowsum[blockIdx.x * 256 + tid] = 0.0f;
  __syncthreads();

  const int c    = (blockIdx.x << 2) + (tid >> 6);    // class id
  const int lane = tid & 63;

  float4 p = ((const float4*)(proto + (size_t)c * FEAT_DIM))[lane];

  const int4 L0 = ((const int4*)lab_s)[lane * 4 + 0];
  const int4 L1 = ((const int4*)lab_s)[lane * 4 + 1];
  const int4 L2 = ((const int4*)lab_s)[lane * 4 + 2];
  const int4 L3 = ((const int4*)lab_s)[lane * 4 + 3];
  unsigned m = 0;
  m |= (L0.x == c) << 0;  m |= (L0.y == c) << 1;
  m |= (L0.z == c) << 2;  m |= (L0.w == c) << 3;
  m |= (L1.x == c) << 4;  m |= (L1.y == c) << 5;
  m |= (L1.z == c) << 6;  m |= (L1.w == c) << 7;
  m |= (L2.x == c) << 8;  m |= (L2.y == c) << 9;
  m |= (L2.z == c) << 10; m |= (L2.w == c) << 11;
  m |= (L3.x == c) << 12; m |= (L3.y == c) << 13;
  m |= (L3.z == c) << 14; m |= (L3.w == c) << 15;

  unsigned long long wm = __ballot(m != 0);
  while (wm) {                           // wave-uniform (rare path)
    const int src = __ffsll((long long)wm) - 1;
    unsigned mm = __shfl(m, src);
    while (mm) {
      const int j = __ffs(mm) - 1;
      mm &= mm - 1;
      const int t = src * 16 + j;        // ascending t = batch order
      float4 f = ((const float4*)(feats + (size_t)t * FEAT_DIM))[lane];
      float4 r;
      r.x = 0.5f * p.x + 0.5f * f.x;
      r.y = 0.5f * p.y + 0.5f * f.y;
      r.z = 0.5f * p.z + 0.5f * f.z;
      r.w = 0.5f * p.w + 0.5f * f.w;
      float ss = r.x * r.x + r.y * r.y + r.z * r.z + r.w * r.w;
#pragma unroll
      for (int off = 32; off; off >>= 1) ss += __shfl_xor(ss, off);
      float inv = 1.0f / fmaxf(sqrtf(ss), 1e-12f);
      p.x = r.x * inv; p.y = r.y * inv; p.z = r.z * inv; p.w = r.w * inv;
    }
    wm &= wm - 1;
  }

  int v = __builtin_amdgcn_cvt_pk_fp8_f32(p.x, p.y, 0, false);
  v = __builtin_amdgcn_cvt_pk_fp8_f32(p.z, p.w, v, true);
  ((int*)(P8 + (size_t)c * FEAT_DIM))[lane] = v;
}

// ---------------------------------------------------------------------------
// Phase 2: fused fp8 GEMM (P * P^T / T) -> exp -> mask -> row sums.
// T3+T4 counted-vmcnt pipeline with a CLEAN vmem stream: the only vmem ops
// in the main chain are the 8 gload_lds per stage (epilogues write LDS
// partials; the single global-atomic flush happens after the last barrier
// and is never drained). WAITV(8) therefore waits exactly for the current
// buffer's loads, which were issued a full phase earlier -> ~0 stall.
// 128x128 tile, BK=128 fp8, dbuf 64 KB + 8 KB partials (2 blocks/CU),
// 4 tasks/block = 8 phases, grid 520 = 8 x 65 bijective XCD swizzle.
// Same barrier/stage ordering R10 already validated for correctness.
// ---------------------------------------------------------------------------
#define BM 128
#define NB (NUM_CLASSES / BM)           // 64 block-rows
#define NTRI (NB * (NB + 1) / 2)        // 2080 triangular tasks
#define NBLK (NTRI / 4)                 // 520 blocks, 4 tasks each
#define LROW 128                        // bytes per LDS row (128 fp8)

#define WAITV(N)                                                              \
  { asm volatile("s_waitcnt vmcnt(" #N ")" ::: "memory");                     \
    __builtin_amdgcn_sched_barrier(0); }
#define BAR() __builtin_amdgcn_s_barrier()

__global__ __launch_bounds__(256, 2) void gemm_rowsum_kernel(
    const unsigned char* __restrict__ P8, float* __restrict__ rowsum) {
  __shared__ __align__(16) char lds[2][2][BM * LROW];  // [buf][A/B] = 64 KB
  __shared__ float Lrow[4][2][BM];                     // [task][wn][row] 4 KB
  __shared__ float Lcol[4][2][BM];                     // [task][wm][col] 4 KB
  __shared__ int   Lbi[4], Lbj[4];

  // XCD-aware bijective swizzle: 520 = 8 * 65
  const int hw  = blockIdx.x;
  const int bid = (hw & 7) * (NBLK / 8) + (hw >> 3);

  // 4 consecutive triangular tasks
  int bi_0, bj_0, bi_1, bj_1, bi_2, bj_2, bi_3, bj_3;
  {
    int rem = bid * 4, bi = 0;
    while (rem >= (NB - bi)) { rem -= (NB - bi); ++bi; }
    int bj = bi + rem;
    bi_0 = bi; bj_0 = bj;
    if (bj + 1 < NB) ++bj; else { ++bi; bj = bi; }
    bi_1 = bi; bj_1 = bj;
    if (bj + 1 < NB) ++bj; else { ++bi; bj = bi; }
    bi_2 = bi; bj_2 = bj;
    if (bj + 1 < NB) ++bj; else { ++bi; bj = bi; }
    bi_3 = bi; bj_3 = bj;
  }

  const int tid  = threadIdx.x;
  const int wid  = tid >> 6;          // 0..3
  const int lane = tid & 63;
  const int wm   = wid >> 1;          // 0..1
  const int wn   = wid & 1;           // 0..1

  if (tid < 4) {
    Lbi[tid] = (tid == 0) ? bi_0 : (tid == 1) ? bi_1 : (tid == 2) ? bi_2 : bi_3;
    Lbj[tid] = (tid == 0) ? bj_0 : (tid == 1) ? bj_1 : (tid == 2) ? bj_2 : bj_3;
  }

  f32x4 acc[4][4] = {};

  const int rloc = lane >> 3;             // 0..7 row within 8-row load
  const int csrc = (lane & 7) ^ rloc;     // pre-swizzled source chunk

#define STAGE(BI, BJ, KT, BUF)                                                \
  {                                                                           \
    const unsigned char* PA_ = P8 + (size_t)((BI) * BM) * FEAT_DIM;           \
    const unsigned char* PB_ = P8 + (size_t)((BJ) * BM) * FEAT_DIM;           \
    _Pragma("unroll")                                                         \
    for (int q = 0; q < 4; ++q) {                                             \
      const int L = wid * 4 + q;          /* 0..15 */                         \
      const int r = L * 8 + rloc;         /* tile row 0..127 */               \
      const size_t go = (size_t)r * FEAT_DIM + (KT) * 128 + csrc * 16;        \
      GLD16(PA_ + go, &lds[BUF][0][L * 1024]);                                \
      GLD16(PB_ + go, &lds[BUF][1][L * 1024]);                                \
    }                                                                         \
  }

  const int g  = lane >> 4;   // 0..3
  const int rl = lane & 15;   // 0..15

#define COMPUTE(BUF)                                                          \
  {                                                                           \
    const char* As = &lds[BUF][0][0];                                         \
    const char* Bs = &lds[BUF][1][0];                                         \
    _Pragma("unroll")                                                         \
    for (int kk = 0; kk < 4; ++kk) {                                          \
      const int cl = 2 * kk + (g >> 1);   /* logical 16B chunk */             \
      const int ib = (g & 1) * 8;         /* inner byte */                    \
      fp8x8 a[4], b[4];                                                       \
      _Pragma("unroll")                                                       \
      for (int mi = 0; mi < 4; ++mi) {                                        \
        const int row = wm * 64 + mi * 16 + rl;                               \
        a[mi] = *(const fp8x8*)(As + row * LROW + ((cl ^ (row & 7)) << 4) + ib);\
      }                                                                       \
      _Pragma("unroll")                                                       \
      for (int ni = 0; ni < 4; ++ni) {                                        \
        const int row = wn * 64 + ni * 16 + rl;                               \
        b[ni] = *(const fp8x8*)(Bs + row * LROW + ((cl ^ (row & 7)) << 4) + ib);\
      }                                                                       \
      _Pragma("unroll")                                                       \
      for (int mi = 0; mi < 4; ++mi)                                          \
        _Pragma("unroll")                                                     \
        for (int ni = 0; ni < 4; ++ni)                                        \
          acc[mi][ni] = __builtin_amdgcn_mfma_f32_16x16x32_fp8_fp8(           \
              a[mi], b[ni], acc[mi][ni], 0, 0, 0);                            \
    }                                                                         \
  }

  // Epilogue calc: exp + reduce, partials -> LDS (NO global atomics here;
  // keeps the vmcnt stream pure staging loads).
#define EPI_CALC(T, BI, BJ)                                                   \
  {                                                                           \
    const bool diag = ((BI) == (BJ));                                         \
    float col[4] = {0.0f, 0.0f, 0.0f, 0.0f};                                  \
    _Pragma("unroll")                                                         \
    for (int mi = 0; mi < 4; ++mi) {                                          \
      _Pragma("unroll")                                                       \
      for (int v = 0; v < 4; ++v) {                                           \
        const int lrow = wm * 64 + mi * 16 + g * 4 + v;                       \
        const int grow = (BI) * BM + lrow;                                    \
        float rs = 0.0f;                                                      \
        _Pragma("unroll")                                                     \
        for (int ni = 0; ni < 4; ++ni) {                                      \
          const int gcol = (BJ) * BM + wn * 64 + ni * 16 + rl;                \
          float e = __expf(10.0f * acc[mi][ni][v]);                           \
          if (diag && grow == gcol) e = 0.0f;                                 \
          rs += e;                                                            \
          col[ni] += e;                                                       \
        }                                                                     \
        rs += __shfl_xor(rs, 1);                                              \
        rs += __shfl_xor(rs, 2);                                              \
        rs += __shfl_xor(rs, 4);                                              \
        rs += __shfl_xor(rs, 8);                                              \
        if (rl == 0) Lrow[T][wn][lrow] = rs;                                  \
      }                                                                       \
    }                                                                         \
    _Pragma("unroll")                                                         \
    for (int ni = 0; ni < 4; ++ni) {                                          \
      float cs = col[ni];                                                     \
      cs += __shfl_xor(cs, 16);                                               \
      cs += __shfl_xor(cs, 32);                                               \
      if (g == 0) Lcol[T][wm][wn * 64 + ni * 16 + rl] = cs;                   \
    }                                                                         \
  }

#define ZEROACC()                                                             \
  {                                                                           \
    _Pragma("unroll")                                                         \
    for (int mi = 0; mi < 4; ++mi)                                            \
      _Pragma("unroll")                                                       \
      for (int ni = 0; ni < 4; ++ni)                                          \
        acc[mi][ni] = (f32x4){0.0f, 0.0f, 0.0f, 0.0f};                        \
  }

  // ---- 8-phase counted-vmcnt pipeline (R10 ordering, clean vmem stream) --
  STAGE(bi_0, bj_0, 0, 0);
  STAGE(bi_0, bj_0, 1, 1);
  // p0
  WAITV(8); BAR(); COMPUTE(0);                                   BAR();
  STAGE(bi_1, bj_1, 0, 0);
  // p1
  WAITV(8); BAR(); COMPUTE(1); EPI_CALC(0, bi_0, bj_0); ZEROACC(); BAR();
  STAGE(bi_1, bj_1, 1, 1);
  // p2
  WAITV(8); BAR(); COMPUTE(0);                                   BAR();
  STAGE(bi_2, bj_2, 0, 0);
  // p3
  WAITV(8); BAR(); COMPUTE(1); EPI_CALC(1, bi_1, bj_1); ZEROACC(); BAR();
  STAGE(bi_2, bj_2, 1, 1);
  // p4
  WAITV(8); BAR(); COMPUTE(0);                                   BAR();
  STAGE(bi_3, bj_3, 0, 0);
  // p5
  WAITV(8); BAR(); COMPUTE(1); EPI_CALC(2, bi_2, bj_2); ZEROACC(); BAR();
  STAGE(bi_3, bj_3, 1, 1);
  // p6
  WAITV(8); BAR(); COMPUTE(0);                                   BAR();
  // p7
  WAITV(0); BAR(); COMPUTE(1); EPI_CALC(3, bi_3, bj_3);

  __syncthreads();                       // Lrow/Lcol/Lbi/Lbj visible

  // ---- single deferred flush: atomics issued once, never drained --------
#pragma unroll
  for (int k = 0; k < 2; ++k) {
    const int idx = tid + k * 256;       // 0..511
    const int T = idx >> 7;              // 0..3
    const int r = idx & 127;
    const int biT = Lbi[T], bjT = Lbj[T];
    atomicAdd(&rowsum[biT * BM + r], Lrow[T][0][r] + Lrow[T][1][r]);
    if (biT != bjT)
      atomicAdd(&rowsum[bjT * BM + r], Lcol[T][0][r] + Lcol[T][1][r]);
  }
}

// ---------------------------------------------------------------------------
// Phase 3: loss = mean(log(rowsum / 8191))
// ---------------------------------------------------------------------------
__global__ __launch_bounds__(256) void finalize_kernel(
    const float* __restrict__ rowsum, float* __restrict__ out) {
  const int tid = threadIdx.x;
  float s = 0.0f;
  for (int i = tid; i < NUM_CLASSES; i += 256) {
    s += logf(rowsum[i] * (1.0f / (float)(NUM_CLASSES - 1)));
  }
#pragma unroll
  for (int off = 32; off; off >>= 1) s += __shfl_xor(s, off);
  __shared__ float red[4];
  if ((tid & 63) == 0) red[tid >> 6] = s;
  __syncthreads();
  if (tid == 0)
    out[0] = (red[0] + red[1] + red[2] + red[3]) * (1.0f / (float)NUM_CLASSES);
}

// ---------------------------------------------------------------------------
extern "C" void kernel_launch(void* const* d_in, const int* in_sizes, int n_in,
                              void* d_out, int out_size, void* d_ws, size_t ws_size,
                              hipStream_t stream) {
  const float* feats  = (const float*)d_in[0];
  const float* proto  = (const float*)d_in[1];
  const int*   labels = (const int*)d_in[2];
  float*       out    = (float*)d_out;

  char* ws = (char*)d_ws;
  unsigned char* P8 = (unsigned char*)ws;                   // 2 MB fp8 P
  float* rowsum = (float*)(ws + (size_t)NUM_CLASSES * FEAT_DIM);

  ema_convert_kernel<<<NUM_CLASSES / 4, 256, 0, stream>>>(feats, proto, labels,
                                                          P8, rowsum);
  gemm_rowsum_kernel<<<NBLK, 256, 0, stream>>>(P8, rowsum);
  finalize_kernel<<<1, 256, 0, stream>>>(rowsum, out);
}